// Round 9
// baseline (832.913 us; speedup 1.0000x reference)
//
#include <hip/hip_runtime.h>
#include <stdint.h>

// d_out (f32) layout: seed [64][3][256] @0, x3 [64][128][256] @49152,
// fps x [64][3][512] @2146304.  x3 region doubles as x1 staging.
#define X3_OFF 49152
#define FPS_OFF 2146304

typedef float v2f __attribute__((ext_vector_type(2)));

// ws (f32) layout: T1 @0, T1s @8192, T3 @16384, T3s @24576 (each [128][64]),
// featT [512][64] @32768.  Total 65536 floats = 256 KB.

// ---------------------------------------------------------------------------
// k_prep: featT[c][b] = feat[b][c]
// ---------------------------------------------------------------------------
__global__ void k_prep(const float* __restrict__ feat, float* __restrict__ ws) {
    int g = blockIdx.x * 256 + threadIdx.x;   // 32768
    int c = g >> 6, b = g & 63;
    ws[32768 + c * 64 + b] = feat[b * 512 + c];
}

// ---------------------------------------------------------------------------
// k_tterms: T[o][b] = sum_c W[o][128+c] * feat[b][c] for the 4 concat weights
// ---------------------------------------------------------------------------
__global__ void k_tterms(const float* __restrict__ w1, const float* __restrict__ ws1,
                         const float* __restrict__ w3, const float* __restrict__ ws3,
                         float* __restrict__ ws) {
    int g = blockIdx.x * 256 + threadIdx.x;   // 32768
    int which = g >> 13;
    int o = (g >> 6) & 127;
    int b = g & 63;
    const float* W = (which == 0) ? w1 : (which == 1) ? ws1
                     : (which == 2) ? w3 : ws3;
    const float* ft = ws + 32768;
    float acc = 0.f;
    for (int c = 0; c < 512; ++c)
        acc = fmaf(W[o * 640 + 128 + c], ft[c * 64 + b], acc);
    ws[which * 8192 + o * 64 + b] = acc;
}

// ---------------------------------------------------------------------------
// k_deconv (v3): x1[b][o][k] = sum_c feat[b][c]*ps_w[c][o][k] + ps_b[o]
// y-blocks=2 (32 batches each) -> psw HBM traffic 128 MB.
// __launch_bounds__(256,2) gives a 256-VGPR budget: acc[32]+temps ~48 regs,
// no spill (R7's acc[32] without bounds regressed).
// ---------------------------------------------------------------------------
__global__ void __launch_bounds__(256, 2)
k_deconv(const float* __restrict__ psw,
         const float* __restrict__ psb,
         const float* __restrict__ ws,
         float* __restrict__ stage) {
    int n = blockIdx.x * 256 + threadIdx.x;   // 32768 = o*256+k
    int b0 = blockIdx.y * 32;
    const float* featT = ws + 32768;
    float acc[32];
    float bias = psb[n >> 8];
#pragma unroll
    for (int j = 0; j < 32; ++j) acc[j] = bias;
    for (int c = 0; c < 512; ++c) {
        float pw = psw[c * 32768 + n];
#pragma unroll
        for (int j = 0; j < 32; ++j)
            acc[j] = fmaf(pw, featT[c * 64 + b0 + j], acc[j]);
    }
#pragma unroll
    for (int j = 0; j < 32; ++j)
        stage[(b0 + j) * 32768 + n] = acc[j];
}

// ---------------------------------------------------------------------------
// gemm8: acc[r] += sum_i S[i][lane] * Wg[(o0+r)*ld + i]  (o0 wave-uniform)
// ---------------------------------------------------------------------------
__device__ __forceinline__ void gemm8(const float* __restrict__ Wg, int ld, int o0,
                                      const float* S, int K, float acc[8], int lane) {
    o0 = __builtin_amdgcn_readfirstlane(o0);   // force SGPR weight addressing
#pragma unroll 4
    for (int i = 0; i < K; ++i) {
        float x = S[i * 64 + lane];
#pragma unroll
        for (int r = 0; r < 8; ++r)
            acc[r] = fmaf(x, Wg[(o0 + r) * ld + i], acc[r]);
    }
}

// ---------------------------------------------------------------------------
// k_fused: per (b, 64-wide k-tile): x1 -> m1 -> m2 -> m3 -> m4/seed.
// ---------------------------------------------------------------------------
struct FusedW {
    const float *m1_w1, *m1_b1, *m1_w2, *m1_b2, *m1_ws, *m1_bs;
    const float *m2_w1, *m2_b1, *m2_w2, *m2_b2, *m2_ws, *m2_bs;
    const float *m3_w1, *m3_b1, *m3_w2, *m3_b2, *m3_ws, *m3_bs;
    const float *m4_w1, *m4_b1, *m4_w2, *m4_b2;
};

__global__ void __launch_bounds__(512)
k_fused(FusedW P, const float* __restrict__ ws, float* __restrict__ fout) {
    int b  = blockIdx.x >> 2;
    int k0 = (blockIdx.x & 3) * 64;
    int lane = threadIdx.x & 63;
    int wave = __builtin_amdgcn_readfirstlane(threadIdx.x >> 6);

    const float* T1  = ws;
    const float* T1s = ws + 8192;
    const float* T3  = ws + 16384;
    const float* T3s = ws + 24576;
    float* stage = fout + X3_OFF + b * 32768;

    __shared__ float Xs[8192];
    __shared__ float Hs[8192];

#pragma unroll
    for (int s = 0; s < 16; ++s) {
        int e = threadIdx.x + s * 512;
        int o = e >> 6, kk = e & 63;
        Xs[e] = stage[o * 256 + k0 + kk];
    }
    __syncthreads();

    float yreg[2][8];

    // ================= m1 =================
#pragma unroll
    for (int half = 0; half < 2; ++half) {
        int o0 = wave * 16 + half * 8;
        float acc[8];
#pragma unroll
        for (int r = 0; r < 8; ++r) acc[r] = T1[(o0 + r) * 64 + b] + P.m1_b1[o0 + r];
        gemm8(P.m1_w1, 640, o0, Xs, 128, acc, lane);
#pragma unroll
        for (int r = 0; r < 8; ++r) Hs[(o0 + r) * 64 + lane] = fmaxf(acc[r], 0.f);
    }
    __syncthreads();
#pragma unroll
    for (int half = 0; half < 2; ++half) {
        int o0 = wave * 16 + half * 8;
        float acc[8];
#pragma unroll
        for (int r = 0; r < 8; ++r)
            acc[r] = T1s[(o0 + r) * 64 + b] + P.m1_b2[o0 + r] + P.m1_bs[o0 + r];
        gemm8(P.m1_w2, 128, o0, Hs, 128, acc, lane);
        gemm8(P.m1_ws, 640, o0, Xs, 128, acc, lane);
#pragma unroll
        for (int r = 0; r < 8; ++r) yreg[half][r] = acc[r];
    }
    __syncthreads();
#pragma unroll
    for (int half = 0; half < 2; ++half) {
        int o0 = wave * 16 + half * 8;
#pragma unroll
        for (int r = 0; r < 8; ++r) Xs[(o0 + r) * 64 + lane] = yreg[half][r];
    }
    __syncthreads();

    // ================= m2 =================
    {
        int o0 = wave * 8;
        float acc[8];
#pragma unroll
        for (int r = 0; r < 8; ++r) acc[r] = P.m2_b1[o0 + r];
        gemm8(P.m2_w1, 128, o0, Xs, 128, acc, lane);
#pragma unroll
        for (int r = 0; r < 8; ++r) Hs[(o0 + r) * 64 + lane] = fmaxf(acc[r], 0.f);
    }
    __syncthreads();
#pragma unroll
    for (int half = 0; half < 2; ++half) {
        int o0 = wave * 16 + half * 8;
        float acc[8];
#pragma unroll
        for (int r = 0; r < 8; ++r) acc[r] = P.m2_b2[o0 + r] + P.m2_bs[o0 + r];
        gemm8(P.m2_w2, 64, o0, Hs, 64, acc, lane);
        gemm8(P.m2_ws, 128, o0, Xs, 128, acc, lane);
#pragma unroll
        for (int r = 0; r < 8; ++r) yreg[half][r] = acc[r];
    }
    __syncthreads();
#pragma unroll
    for (int half = 0; half < 2; ++half) {
        int o0 = wave * 16 + half * 8;
#pragma unroll
        for (int r = 0; r < 8; ++r) Xs[(o0 + r) * 64 + lane] = yreg[half][r];
    }
    __syncthreads();

    // ================= m3 =================
#pragma unroll
    for (int half = 0; half < 2; ++half) {
        int o0 = wave * 16 + half * 8;
        float acc[8];
#pragma unroll
        for (int r = 0; r < 8; ++r) acc[r] = T3[(o0 + r) * 64 + b] + P.m3_b1[o0 + r];
        gemm8(P.m3_w1, 640, o0, Xs, 128, acc, lane);
#pragma unroll
        for (int r = 0; r < 8; ++r) Hs[(o0 + r) * 64 + lane] = fmaxf(acc[r], 0.f);
    }
    __syncthreads();
#pragma unroll
    for (int half = 0; half < 2; ++half) {
        int o0 = wave * 16 + half * 8;
        float acc[8];
#pragma unroll
        for (int r = 0; r < 8; ++r)
            acc[r] = T3s[(o0 + r) * 64 + b] + P.m3_b2[o0 + r] + P.m3_bs[o0 + r];
        gemm8(P.m3_w2, 128, o0, Hs, 128, acc, lane);
        gemm8(P.m3_ws, 640, o0, Xs, 128, acc, lane);
#pragma unroll
        for (int r = 0; r < 8; ++r) yreg[half][r] = acc[r];
    }
    __syncthreads();
#pragma unroll
    for (int half = 0; half < 2; ++half) {
        int o0 = wave * 16 + half * 8;
#pragma unroll
        for (int r = 0; r < 8; ++r) {
            Xs[(o0 + r) * 64 + lane] = yreg[half][r];
            stage[(o0 + r) * 256 + k0 + lane] = yreg[half][r];
        }
    }
    __syncthreads();

    // ================= m4 / seed =================
    {
        int o0 = wave * 8;
        float acc[8];
#pragma unroll
        for (int r = 0; r < 8; ++r) acc[r] = P.m4_b1[o0 + r];
        gemm8(P.m4_w1, 128, o0, Xs, 128, acc, lane);
#pragma unroll
        for (int r = 0; r < 8; ++r) Hs[(o0 + r) * 64 + lane] = fmaxf(acc[r], 0.f);
    }
    __syncthreads();
    if (wave < 3) {
        int d = wave;
        float s = P.m4_b2[d];
        for (int j = 0; j < 64; ++j)
            s = fmaf(Hs[j * 64 + lane], P.m4_w2[d * 64 + j], s);
        fout[b * 768 + d * 256 + k0 + lane] = s;
    }
}

// ---------------------------------------------------------------------------
// DPP wave-64 reductions (row_shr 1/2/4/8 + row_bcast15 + row_bcast31);
// result in lane 63.
// ---------------------------------------------------------------------------
__device__ __forceinline__ unsigned wave_max_u32_l63(unsigned v) {
    unsigned t;
    t = (unsigned)__builtin_amdgcn_update_dpp(0, (int)v, 0x111, 0xf, 0xf, false); v = t > v ? t : v;
    t = (unsigned)__builtin_amdgcn_update_dpp(0, (int)v, 0x112, 0xf, 0xf, false); v = t > v ? t : v;
    t = (unsigned)__builtin_amdgcn_update_dpp(0, (int)v, 0x114, 0xf, 0xf, false); v = t > v ? t : v;
    t = (unsigned)__builtin_amdgcn_update_dpp(0, (int)v, 0x118, 0xf, 0xf, false); v = t > v ? t : v;
    t = (unsigned)__builtin_amdgcn_update_dpp(0, (int)v, 0x142, 0xa, 0xf, false); v = t > v ? t : v;
    t = (unsigned)__builtin_amdgcn_update_dpp(0, (int)v, 0x143, 0xc, 0xf, false); v = t > v ? t : v;
    return v;
}
__device__ __forceinline__ unsigned wave_min_u32_l63(unsigned v) {
    unsigned t;
    t = (unsigned)__builtin_amdgcn_update_dpp(-1, (int)v, 0x111, 0xf, 0xf, false); v = t < v ? t : v;
    t = (unsigned)__builtin_amdgcn_update_dpp(-1, (int)v, 0x112, 0xf, 0xf, false); v = t < v ? t : v;
    t = (unsigned)__builtin_amdgcn_update_dpp(-1, (int)v, 0x114, 0xf, 0xf, false); v = t < v ? t : v;
    t = (unsigned)__builtin_amdgcn_update_dpp(-1, (int)v, 0x118, 0xf, 0xf, false); v = t < v ? t : v;
    t = (unsigned)__builtin_amdgcn_update_dpp(-1, (int)v, 0x142, 0xa, 0xf, false); v = t < v ? t : v;
    t = (unsigned)__builtin_amdgcn_update_dpp(-1, (int)v, 0x143, 0xc, 0xf, false); v = t < v ? t : v;
    return v;
}

// ---------------------------------------------------------------------------
// k_fps (v5 = v4 + packed-f32 dist update): one block of 256 threads per
// batch; 4352 pts = 256*17 in registers (as 9 float2 pairs; slot 17 = dummy
// with dist pinned at -1) AND mirrored in LDS (centroid broadcast + gather).
// v_pk_add/mul_f32 halve the sub/mul/add issue; fmin/cmp/sel stay scalar.
// Per-half IEEE f32 => numerics identical to v4 (exact numpy rounding kept).
// ---------------------------------------------------------------------------
__global__ void __launch_bounds__(256)
k_fps(const float* __restrict__ seed, const float* __restrict__ partial,
      float* __restrict__ outx) {
    int b = blockIdx.x;
    int tid = threadIdx.x;        // 0..255
    int lane = tid & 63;
    int wv = tid >> 6;            // 0..3

    __shared__ float pts[4352 * 3];          // [idx][3]
    __shared__ unsigned long long cand[2][4];
    __shared__ int fars[512];

    // stage seed [b][3][256] -> pts[idx<256]
    pts[tid * 3 + 0] = seed[b * 768 + tid];
    pts[tid * 3 + 1] = seed[b * 768 + 256 + tid];
    pts[tid * 3 + 2] = seed[b * 768 + 512 + tid];
    // stage partial [b][4096][3] -> pts[256..4351]  (linear 12288 dwords)
#pragma unroll
    for (int j = 0; j < 48; ++j) {
        int e = tid + j * 256;
        pts[768 + e] = partial[b * 12288 + e];
    }
    if (tid == 0) fars[0] = 0;
    __syncthreads();

    // pair j holds global idx g0 = (2j)*256+tid (.x) and g1 = (2j+1)*256+tid
    // (.y); pair 8's .y is a dummy (dist pinned -1, never selected).
    v2f px[9], py[9], pz[9], dist[9];
#pragma unroll
    for (int j = 0; j < 9; ++j) {
        int g0 = (2 * j) * 256 + tid;
        px[j].x = pts[g0 * 3 + 0];
        py[j].x = pts[g0 * 3 + 1];
        pz[j].x = pts[g0 * 3 + 2];
        dist[j].x = 1e10f;
        if (j < 8) {
            int g1 = (2 * j + 1) * 256 + tid;
            px[j].y = pts[g1 * 3 + 0];
            py[j].y = pts[g1 * 3 + 1];
            pz[j].y = pts[g1 * 3 + 2];
            dist[j].y = 1e10f;
        } else {
            px[j].y = 0.f; py[j].y = 0.f; pz[j].y = 0.f;
            dist[j].y = -1.0f;     // dummy: min(-1, d>=0) stays -1
        }
    }
    float cx = pts[0], cy = pts[1], cz = pts[2];

    for (int t = 0; t < 511; ++t) {
        v2f c2x = {cx, cx}, c2y = {cy, cy}, c2z = {cz, cz};
        float bv = -1.0f; int bg = 0;
#pragma unroll
        for (int j = 0; j < 9; ++j) {
            v2f dx = px[j] - c2x;           // v_pk_add_f32 (neg mod)
            v2f dy = py[j] - c2y;
            v2f dz = pz[j] - c2z;
            v2f d = (dx * dx + dy * dy) + dz * dz;   // pk mul/add, no fma
            // scalar min + argmax (first-hit strict > keeps min g)
            float d0 = fminf(dist[j].x, d.x);
            float d1 = fminf(dist[j].y, d.y);
            dist[j].x = d0; dist[j].y = d1;
            if (d0 > bv) { bv = d0; bg = (2 * j) * 256 + tid; }
            if (d1 > bv) { bv = d1; bg = (2 * j + 1) * 256 + tid; }
        }
        // phase 1: wave max of dist bits (dist >= 0 -> u32 order == f32 order)
        unsigned mv = wave_max_u32_l63(__float_as_uint(bv));
        unsigned maxbits = (unsigned)__builtin_amdgcn_readlane((int)mv, 63);
        // phase 2: wave min of candidate global index among exact-max ties
        unsigned cg = (__float_as_uint(bv) == maxbits) ? (unsigned)bg : 0xFFFFFFFFu;
        unsigned mgv = wave_min_u32_l63(cg);
        unsigned big = (unsigned)__builtin_amdgcn_readlane((int)mgv, 63);

        if (lane == 0)
            cand[t & 1][wv] = (((unsigned long long)maxbits) << 32) |
                              (unsigned long long)(8191u - big);
        __syncthreads();
        unsigned long long U0 = cand[t & 1][0];
        unsigned long long U1 = cand[t & 1][1];
        unsigned long long U2 = cand[t & 1][2];
        unsigned long long U3 = cand[t & 1][3];
        if (U1 > U0) U0 = U1;
        if (U3 > U2) U2 = U3;
        if (U2 > U0) U0 = U2;
        int bi = 8191 - (int)(U0 & 8191ull);
        cx = pts[bi * 3 + 0]; cy = pts[bi * 3 + 1]; cz = pts[bi * 3 + 2];
        if (tid == 0) fars[t + 1] = bi;
    }
    __syncthreads();

    // gather outputs: x [b][3][512]
#pragma unroll
    for (int j = 0; j < 2; ++j) {
        int n = tid + j * 256;
        int idx = fars[n];
        int ob = b * 1536 + n;
        outx[ob]        = pts[idx * 3 + 0];
        outx[ob + 512]  = pts[idx * 3 + 1];
        outx[ob + 1024] = pts[idx * 3 + 2];
    }
}

// ---------------------------------------------------------------------------
extern "C" void kernel_launch(void* const* d_in, const int* in_sizes, int n_in,
                              void* d_out, int out_size, void* d_ws, size_t ws_size,
                              hipStream_t stream) {
    (void)in_sizes; (void)n_in; (void)out_size; (void)ws_size;
    const float* feat    = (const float*)d_in[0];
    const float* partial = (const float*)d_in[3];
    const float* psw     = (const float*)d_in[4];
    const float* psb     = (const float*)d_in[5];

    FusedW P;
    P.m1_w1 = (const float*)d_in[6];  P.m1_b1 = (const float*)d_in[7];
    P.m1_w2 = (const float*)d_in[8];  P.m1_b2 = (const float*)d_in[9];
    P.m1_ws = (const float*)d_in[10]; P.m1_bs = (const float*)d_in[11];
    P.m2_w1 = (const float*)d_in[12]; P.m2_b1 = (const float*)d_in[13];
    P.m2_w2 = (const float*)d_in[14]; P.m2_b2 = (const float*)d_in[15];
    P.m2_ws = (const float*)d_in[16]; P.m2_bs = (const float*)d_in[17];
    P.m3_w1 = (const float*)d_in[18]; P.m3_b1 = (const float*)d_in[19];
    P.m3_w2 = (const float*)d_in[20]; P.m3_b2 = (const float*)d_in[21];
    P.m3_ws = (const float*)d_in[22]; P.m3_bs = (const float*)d_in[23];
    P.m4_w1 = (const float*)d_in[24]; P.m4_b1 = (const float*)d_in[25];
    P.m4_w2 = (const float*)d_in[26]; P.m4_b2 = (const float*)d_in[27];

    float* W = (float*)d_ws;
    float* out = (float*)d_out;

    k_prep<<<dim3(128), dim3(256), 0, stream>>>(feat, W);
    k_tterms<<<dim3(128), dim3(256), 0, stream>>>(P.m1_w1, P.m1_ws, P.m3_w1, P.m3_ws, W);
    k_deconv<<<dim3(128, 2), dim3(256), 0, stream>>>(psw, psb, W, out + X3_OFF);
    k_fused<<<dim3(256), dim3(512), 0, stream>>>(P, W, out);
    k_fps<<<dim3(64), dim3(256), 0, stream>>>(out, partial, out + FPS_OFF);
}